// Round 8
// baseline (494.974 us; speedup 1.0000x reference)
//
#include <hip/hip_runtime.h>
#include <hip/hip_bf16.h>
#include <math.h>

#define N_NODES 100000
#define EPS 1e-5f
#define B2SH 11
#define NPB2 2048
#define NBUCK2 ((N_NODES + NPB2 - 1) / NPB2)  // 49
#define NPART 256

typedef __attribute__((ext_vector_type(8))) short bf16x8;
typedef __attribute__((ext_vector_type(4))) float f32x4;
typedef __attribute__((ext_vector_type(2))) float f32x2;

__device__ __forceinline__ unsigned short fbits(float f) {
    __hip_bfloat16 h = __float2bfloat16(f);
    return *reinterpret_cast<unsigned short*>(&h);
}
__device__ __forceinline__ void stv(float* p, float y) { *p = y; }
__device__ __forceinline__ void stv(__hip_bfloat16* p, float y) { *p = __float2bfloat16(y); }
__device__ __forceinline__ unsigned char f8enc(float y) {
    return (unsigned char)((unsigned int)__builtin_amdgcn_cvt_pk_fp8_f32(y, y, 0, false) & 0xffu);
}

// ---------------- atomic-free two-level CSR build ----------------
__global__ void part_hist(const int* __restrict__ dst, int E, int* __restrict__ blkhist) {
    __shared__ int h[NBUCK2];
    int b = blockIdx.x;
    int slice = (E + NPART - 1) / NPART;
    int s0 = b * slice;
    int s1 = min(E, s0 + slice);
    for (int i = threadIdx.x; i < NBUCK2; i += 256) h[i] = 0;
    __syncthreads();
    for (int e = s0 + threadIdx.x; e < s1; e += 256) atomicAdd(&h[dst[e] >> B2SH], 1);
    __syncthreads();
    for (int i = threadIdx.x; i < NBUCK2; i += 256) blkhist[i * NPART + b] = h[i];
}

__global__ void part_offsets(const int* __restrict__ blkhist, int* __restrict__ blkoffs,
                             int* __restrict__ bbase2, int* __restrict__ row_ptr, int E) {
    __shared__ int tot[NBUCK2];
    __shared__ int sbase[NBUCK2 + 1];
    int j = threadIdx.x;
    if (j < NBUCK2) {
        int run = 0;
#pragma unroll 8
        for (int b = 0; b < NPART; ++b) {
            blkoffs[j * NPART + b] = run;
            run += blkhist[j * NPART + b];
        }
        tot[j] = run;
    }
    __syncthreads();
    if (j == 0) {
        int run = 0;
        for (int i = 0; i < NBUCK2; ++i) {
            sbase[i] = run;
            run += tot[i];
        }
        sbase[NBUCK2] = run;
        row_ptr[N_NODES] = E;
    }
    __syncthreads();
    if (j <= NBUCK2) bbase2[j] = sbase[j];
    if (j < NBUCK2) {
        int base = sbase[j];
#pragma unroll 8
        for (int b = 0; b < NPART; ++b) blkoffs[j * NPART + b] += base;
    }
}

__global__ void part_scatter(const int* __restrict__ src, const int* __restrict__ dst, int E,
                             const int* __restrict__ blkoffs, unsigned int* __restrict__ pairs) {
    __shared__ int pos[NBUCK2];
    int b = blockIdx.x;
    int slice = (E + NPART - 1) / NPART;
    int s0 = b * slice;
    int s1 = min(E, s0 + slice);
    for (int i = threadIdx.x; i < NBUCK2; i += 256) pos[i] = blkoffs[i * NPART + b];
    __syncthreads();
    for (int e = s0 + threadIdx.x; e < s1; e += 256) {
        int d = dst[e];
        int jb = d >> B2SH;
        int p = atomicAdd(&pos[jb], 1);
        pairs[p] = ((unsigned int)src[e] << B2SH) | (unsigned int)(d & (NPB2 - 1));
    }
}

__global__ __launch_bounds__(1024) void bucket_build2(const unsigned int* __restrict__ pairs,
                                                      const int* __restrict__ bbase2,
                                                      int* __restrict__ row_ptr,
                                                      int* __restrict__ col) {
    __shared__ int lcnt[NPB2];
    __shared__ int lofs[NPB2];
    __shared__ int part[1024];
    int bk = blockIdx.x;
    int base = bbase2[bk];
    int cntb = bbase2[bk + 1] - base;
    int node0 = bk << B2SH;
    int t = threadIdx.x;
    lcnt[t] = 0;
    lcnt[t + 1024] = 0;
    __syncthreads();
    for (int i = t; i < cntb; i += 1024) atomicAdd(&lcnt[pairs[base + i] & (NPB2 - 1)], 1);
    __syncthreads();
    int a0 = lcnt[2 * t], a1 = lcnt[2 * t + 1];
    part[t] = a0 + a1;
    __syncthreads();
    for (int off = 1; off < 1024; off <<= 1) {
        int v = (t >= off) ? part[t - off] : 0;
        __syncthreads();
        part[t] += v;
        __syncthreads();
    }
    int excl = part[t] - (a0 + a1);
    lofs[2 * t] = excl;
    lofs[2 * t + 1] = excl + a0;
    __syncthreads();
#pragma unroll
    for (int k = 0; k < 2; ++k) {
        int ln = 2 * t + k;
        int node = node0 + ln;
        if (node < N_NODES) row_ptr[node] = base + lofs[ln];
    }
    lcnt[t] = 0;
    lcnt[t + 1024] = 0;
    __syncthreads();
    for (int i = t; i < cntb; i += 1024) {
        unsigned int v = pairs[base + i];
        int ld = v & (NPB2 - 1);
        int s = v >> B2SH;
        int p = base + lofs[ld] + atomicAdd(&lcnt[ld], 1);
        col[p] = s;
    }
}

// ---------------- aggregation ----------------
// layer1: x fp32, d=9; 7 lane-groups of 9; predicated unroll of stride-7 walk
__global__ void agg9_kernel(const float* __restrict__ x, const int* __restrict__ row_ptr,
                            const int* __restrict__ col, float* __restrict__ mean, int n) {
    int node = (blockIdx.x * blockDim.x + threadIdx.x) >> 6;
    int lane = threadIdx.x & 63;
    int wv = threadIdx.x >> 6;
    __shared__ float red[4][64];
    float acc = 0.f;
    int start = 0, end = 0;
    if (node < n) {
        start = row_ptr[node];
        end = row_ptr[node + 1];
        int g = lane / 9;
        int f = lane - g * 9;
        if (g < 7 && end > start) {
            for (int p = start + g; p < end; p += 28) {
#pragma unroll
                for (int i = 0; i < 4; ++i) {
                    int q = p + i * 7;
                    int idx = (q < end) ? q : end - 1;
                    float v = x[(size_t)col[idx] * 9 + f];
                    if (q >= end) v = 0.f;
                    acc += v;
                }
            }
        }
    }
    red[wv][lane] = acc;
    __syncthreads();
    if (node < n && lane < 9) {
        float s = red[wv][lane];
#pragma unroll
        for (int k = 1; k < 7; ++k) s += red[wv][lane + 9 * k];
        float inv = 1.f / fmaxf((float)(end - start), 1.f);
        mean[(size_t)node * 9 + lane] = s * inv;
    }
}

// packed fp8 -> f32 accumulate of one 16B chunk into 16 accumulators
__device__ __forceinline__ void acc16_fp8(const uint4& v, float* acc) {
#pragma unroll
    for (int d = 0; d < 4; ++d) {
        unsigned int u = (&v.x)[d];
        f32x2 a = __builtin_amdgcn_cvt_pk_f32_fp8(u, false);
        f32x2 b = __builtin_amdgcn_cvt_pk_f32_fp8(u, true);
        acc[d * 4 + 0] += a[0];
        acc[d * 4 + 1] += a[1];
        acc[d * 4 + 2] += b[0];
        acc[d * 4 + 3] += b[1];
    }
}

// fp8 d=64, 4 nodes per wave: lane = (e<<2)|c, e in [0,16) edge-slot, c in [0,4) 16B chunk.
// Per batch: 4 col loads + 4 uint4 gathers in flight before any convert.
__global__ void agg64_kernel(const unsigned char* __restrict__ h8, const int* __restrict__ row_ptr,
                             const int* __restrict__ col, unsigned short* __restrict__ mean, int n) {
    int wid = (blockIdx.x * blockDim.x + threadIdx.x) >> 6;
    int lane = threadIdx.x & 63;
    int e = lane >> 2, c = lane & 3;
    int nb = wid * 4;
    if (nb >= n) return;
    int s[4], en[4];
#pragma unroll
    for (int j = 0; j < 4; ++j) {
        int node = nb + j;
        if (node < n) {
            s[j] = row_ptr[node];
            en[j] = row_ptr[node + 1];
        } else {
            s[j] = 0;
            en[j] = 0;
        }
    }
    int mx = max(max(en[0] - s[0], en[1] - s[1]), max(en[2] - s[2], en[3] - s[3]));
    float acc[4][16];
#pragma unroll
    for (int j = 0; j < 4; ++j)
#pragma unroll
        for (int k = 0; k < 16; ++k) acc[j][k] = 0.f;
    const unsigned char* hc = h8 + c * 16;
    for (int b = 0; b < mx; b += 16) {
        uint4 v[4];
        bool m[4];
#pragma unroll
        for (int j = 0; j < 4; ++j) {
            int q = s[j] + b + e;
            m[j] = q < en[j];
            int ci = m[j] ? q : s[j];
            unsigned int cv = (unsigned int)col[ci];
            cv = (cv < (unsigned int)n) ? cv : 0u;
            v[j] = *(const uint4*)(hc + ((size_t)cv << 6));
        }
#pragma unroll
        for (int j = 0; j < 4; ++j) {
            if (!m[j]) v[j] = (uint4){0u, 0u, 0u, 0u};
            acc16_fp8(v[j], acc[j]);
        }
    }
#pragma unroll
    for (int j = 0; j < 4; ++j)
#pragma unroll
        for (int k = 0; k < 16; ++k) {
            acc[j][k] += __shfl_xor(acc[j][k], 4);
            acc[j][k] += __shfl_xor(acc[j][k], 8);
            acc[j][k] += __shfl_xor(acc[j][k], 16);
            acc[j][k] += __shfl_xor(acc[j][k], 32);
        }
    if (e == 0) {
#pragma unroll
        for (int j = 0; j < 4; ++j) {
            int node = nb + j;
            if (node >= n) continue;
            float inv = 1.f / fmaxf((float)(en[j] - s[j]), 1.f);
            unsigned int w[8];
#pragma unroll
            for (int k = 0; k < 8; ++k) {
                unsigned int lo = fbits(acc[j][2 * k] * inv);
                unsigned int hi = fbits(acc[j][2 * k + 1] * inv);
                w[k] = lo | (hi << 16);
            }
            unsigned short* mrow = mean + (size_t)node * 64 + c * 16;
            *(uint4*)(mrow) = (uint4){w[0], w[1], w[2], w[3]};
            *(uint4*)(mrow + 8) = (uint4){w[4], w[5], w[6], w[7]};
        }
    }
}

// fp8 d=128, 4 nodes per wave: lane = (e<<3)|c, e in [0,8) edge-slot, c in [0,8) chunk.
__global__ void agg128_kernel(const unsigned char* __restrict__ h8, const int* __restrict__ row_ptr,
                              const int* __restrict__ col, unsigned short* __restrict__ mean, int n) {
    int wid = (blockIdx.x * blockDim.x + threadIdx.x) >> 6;
    int lane = threadIdx.x & 63;
    int e = lane >> 3, c = lane & 7;
    int nb = wid * 4;
    if (nb >= n) return;
    int s[4], en[4];
#pragma unroll
    for (int j = 0; j < 4; ++j) {
        int node = nb + j;
        if (node < n) {
            s[j] = row_ptr[node];
            en[j] = row_ptr[node + 1];
        } else {
            s[j] = 0;
            en[j] = 0;
        }
    }
    int mx = max(max(en[0] - s[0], en[1] - s[1]), max(en[2] - s[2], en[3] - s[3]));
    float acc[4][16];
#pragma unroll
    for (int j = 0; j < 4; ++j)
#pragma unroll
        for (int k = 0; k < 16; ++k) acc[j][k] = 0.f;
    const unsigned char* hc = h8 + c * 16;
    for (int b = 0; b < mx; b += 8) {
        uint4 v[4];
        bool m[4];
#pragma unroll
        for (int j = 0; j < 4; ++j) {
            int q = s[j] + b + e;
            m[j] = q < en[j];
            int ci = m[j] ? q : s[j];
            unsigned int cv = (unsigned int)col[ci];
            cv = (cv < (unsigned int)n) ? cv : 0u;
            v[j] = *(const uint4*)(hc + ((size_t)cv << 7));
        }
#pragma unroll
        for (int j = 0; j < 4; ++j) {
            if (!m[j]) v[j] = (uint4){0u, 0u, 0u, 0u};
            acc16_fp8(v[j], acc[j]);
        }
    }
#pragma unroll
    for (int j = 0; j < 4; ++j)
#pragma unroll
        for (int k = 0; k < 16; ++k) {
            acc[j][k] += __shfl_xor(acc[j][k], 8);
            acc[j][k] += __shfl_xor(acc[j][k], 16);
            acc[j][k] += __shfl_xor(acc[j][k], 32);
        }
    if (e == 0) {
#pragma unroll
        for (int j = 0; j < 4; ++j) {
            int node = nb + j;
            if (node >= n) continue;
            float inv = 1.f / fmaxf((float)(en[j] - s[j]), 1.f);
            unsigned int w[8];
#pragma unroll
            for (int k = 0; k < 8; ++k) {
                unsigned int lo = fbits(acc[j][2 * k] * inv);
                unsigned int hi = fbits(acc[j][2 * k + 1] * inv);
                w[k] = lo | (hi << 16);
            }
            unsigned short* mrow = mean + (size_t)node * 128 + c * 16;
            *(uint4*)(mrow) = (uint4){w[0], w[1], w[2], w[3]};
            *(uint4*)(mrow + 8) = (uint4){w[4], w[5], w[6], w[7]};
        }
    }
}

// ---------------- weight prep ----------------
__global__ void wtrans_kernel(const float* __restrict__ wl, const float* __restrict__ wr,
                              int din, int dout, float* __restrict__ wt) {
    int i = blockIdx.x * blockDim.x + threadIdx.x;
    int K2 = 2 * din;
    if (i >= K2 * dout) return;
    int k = i / dout, j = i % dout;
    wt[k * dout + j] = (k < din) ? wl[j * din + k] : wr[j * din + (k - din)];
}

__global__ void packw_kernel(const float* __restrict__ wl, const float* __restrict__ wr,
                             int din, unsigned short* __restrict__ bpack) {
    int K2 = 2 * din;
    int total = K2 * 128;
    int i = blockIdx.x * 256 + threadIdx.x;
    if (i >= total) return;
    int e = i & 7;
    int lane = (i >> 3) & 63;
    int rest = i >> 9;
    int KSTEPS = din / 16;
    int t = rest / KSTEPS, ks = rest % KSTEPS;
    int j = t * 16 + (lane & 15);
    int k = ks * 32 + (lane >> 4) * 8 + e;
    float w = (k < din) ? wl[j * din + k] : wr[j * din + (k - din)];
    bpack[i] = fbits(w);
}

// ---------------- layer1 fp32 linear + LN + ReLU (+ fp8 shadow) ----------------
template <int DIN, int DOUT, bool RELU, typename OT>
__global__ __launch_bounds__(256) void linear_ln_kernel(
    const float* __restrict__ meanp, const float* __restrict__ hp,
    const float* __restrict__ wt, const float* __restrict__ bias,
    const float* __restrict__ g, const float* __restrict__ be,
    OT* __restrict__ out, unsigned char* __restrict__ out8, int n) {
    constexpr int K2 = 2 * DIN;
    constexpr int NCOL = DOUT / 4;
    constexpr int NROW = 256 / NCOL;
    constexpr int TN = 4 * NROW;
    constexpr int ASTR = TN + 4;
    constexpr int OSTR = DOUT + 4;
    constexpr int SMEMF = (K2 * ASTR > TN * OSTR) ? K2 * ASTR : TN * OSTR;
    __shared__ float smem[SMEMF];

    int tid = threadIdx.x;
    int n0base = blockIdx.x * TN;

    for (int idx = tid; idx < TN * K2; idx += 256) {
        int nn = idx / K2;
        int k = idx % K2;
        int node = n0base + nn;
        float v = 0.f;
        if (node < n)
            v = (k < DIN) ? meanp[(size_t)node * DIN + k] : hp[(size_t)node * DIN + (k - DIN)];
        smem[k * ASTR + nn] = v;
    }
    __syncthreads();

    int colt = tid % NCOL;
    int rowt = tid / NCOL;
    int j0 = colt * 4;
    int nn0 = rowt * 4;

    float acc[4][4];
#pragma unroll
    for (int i = 0; i < 4; ++i)
#pragma unroll
        for (int j = 0; j < 4; ++j) acc[i][j] = 0.f;

#pragma unroll 2
    for (int k = 0; k < K2; ++k) {
        float4 a = *(const float4*)&smem[k * ASTR + nn0];
        float4 w = *(const float4*)&wt[k * DOUT + j0];
        acc[0][0] = fmaf(a.x, w.x, acc[0][0]);
        acc[0][1] = fmaf(a.x, w.y, acc[0][1]);
        acc[0][2] = fmaf(a.x, w.z, acc[0][2]);
        acc[0][3] = fmaf(a.x, w.w, acc[0][3]);
        acc[1][0] = fmaf(a.y, w.x, acc[1][0]);
        acc[1][1] = fmaf(a.y, w.y, acc[1][1]);
        acc[1][2] = fmaf(a.y, w.z, acc[1][2]);
        acc[1][3] = fmaf(a.y, w.w, acc[1][3]);
        acc[2][0] = fmaf(a.z, w.x, acc[2][0]);
        acc[2][1] = fmaf(a.z, w.y, acc[2][1]);
        acc[2][2] = fmaf(a.z, w.z, acc[2][2]);
        acc[2][3] = fmaf(a.z, w.w, acc[2][3]);
        acc[3][0] = fmaf(a.w, w.x, acc[3][0]);
        acc[3][1] = fmaf(a.w, w.y, acc[3][1]);
        acc[3][2] = fmaf(a.w, w.z, acc[3][2]);
        acc[3][3] = fmaf(a.w, w.w, acc[3][3]);
    }
    __syncthreads();

    float4 bj = *(const float4*)&bias[j0];
#pragma unroll
    for (int i = 0; i < 4; ++i) {
        float4 o;
        o.x = acc[i][0] + bj.x;
        o.y = acc[i][1] + bj.y;
        o.z = acc[i][2] + bj.z;
        o.w = acc[i][3] + bj.w;
        *(float4*)&smem[(nn0 + i) * OSTR + j0] = o;
    }
    __syncthreads();

    int wid = tid >> 6, lane = tid & 63;
    for (int nn = wid; nn < TN; nn += 4) {
        int node = n0base + nn;
        if (node >= n) continue;
        float v0 = smem[nn * OSTR + lane];
        float v1 = (DOUT == 128) ? smem[nn * OSTR + 64 + lane] : 0.f;
        float s = v0 + v1;
        float ss = v0 * v0 + v1 * v1;
#pragma unroll
        for (int off = 32; off > 0; off >>= 1) {
            s += __shfl_xor(s, off);
            ss += __shfl_xor(ss, off);
        }
        float mu = s / DOUT;
        float var = ss / DOUT - mu * mu;
        float inv = rsqrtf(var + EPS);
        float y0 = (v0 - mu) * inv * g[lane] + be[lane];
        if (RELU) y0 = fmaxf(y0, 0.f);
        stv(&out[(size_t)node * DOUT + lane], y0);
        if (out8) out8[(size_t)node * DOUT + lane] = f8enc(y0);
        if (DOUT == 128) {
            float y1 = (v1 - mu) * inv * g[64 + lane] + be[64 + lane];
            if (RELU) y1 = fmaxf(y1, 0.f);
            stv(&out[(size_t)node * DOUT + 64 + lane], y1);
            if (out8) out8[(size_t)node * DOUT + 64 + lane] = f8enc(y1);
        }
    }
}

// ---------------- bf16 MFMA linear (concat-K) + LN + optional ReLU + fp8 shadow
template <int DIN, bool RELU, typename OT>
__global__ __launch_bounds__(256) void mfma_linear_ln(
    const unsigned short* __restrict__ meanb, const unsigned short* __restrict__ hb,
    const unsigned short* __restrict__ bpack, const float* __restrict__ bias,
    const float* __restrict__ g, const float* __restrict__ be, OT* __restrict__ out,
    unsigned char* __restrict__ out8, int n) {
    constexpr int KSTEPS = DIN / 16;
    int tid = threadIdx.x;
    int w = tid >> 6, l = tid & 63;
    int n0 = blockIdx.x * 64 + w * 16;
    int arow = l & 15;
    int koff = (l >> 4) * 8;
    int anode = n0 + arow;
    if (anode >= n) anode = n - 1;
    const unsigned short* mrow = meanb + (size_t)anode * DIN;
    const unsigned short* hrow = hb + (size_t)anode * DIN;

    f32x4 acc[8];
#pragma unroll
    for (int t = 0; t < 8; ++t) acc[t] = (f32x4){0.f, 0.f, 0.f, 0.f};

#pragma unroll
    for (int ks = 0; ks < KSTEPS; ++ks) {
        int k = ks * 32 + koff;
        const unsigned short* ap = (k < DIN) ? (mrow + k) : (hrow + (k - DIN));
        bf16x8 a = *(const bf16x8*)ap;
#pragma unroll
        for (int t = 0; t < 8; ++t) {
            bf16x8 b = *(const bf16x8*)(bpack + (((size_t)t * KSTEPS + ks) * 64 + l) * 8);
            acc[t] = __builtin_amdgcn_mfma_f32_16x16x32_bf16(a, b, acc[t], 0, 0, 0);
        }
    }

    int jbase = l & 15;
    float bj[8], gj[8], bej[8];
#pragma unroll
    for (int t = 0; t < 8; ++t) {
        bj[t] = bias[t * 16 + jbase];
        gj[t] = g[t * 16 + jbase];
        bej[t] = be[t * 16 + jbase];
    }
#pragma unroll
    for (int r = 0; r < 4; ++r) {
        float v[8];
        float s = 0.f, ss = 0.f;
#pragma unroll
        for (int t = 0; t < 8; ++t) {
            v[t] = acc[t][r] + bj[t];
            s += v[t];
            ss += v[t] * v[t];
        }
#pragma unroll
        for (int off = 1; off < 16; off <<= 1) {
            s += __shfl_xor(s, off);
            ss += __shfl_xor(ss, off);
        }
        float mu = s * (1.f / 128.f);
        float var = ss * (1.f / 128.f) - mu * mu;
        float inv = rsqrtf(var + EPS);
        int node = n0 + (l >> 4) * 4 + r;
        if (node < n) {
#pragma unroll
            for (int t = 0; t < 8; ++t) {
                float y = (v[t] - mu) * inv * gj[t] + bej[t];
                if (RELU) y = fmaxf(y, 0.f);
                stv(&out[(size_t)node * 128 + t * 16 + jbase], y);
                if (out8) out8[(size_t)node * 128 + t * 16 + jbase] = f8enc(y);
            }
        }
    }
}

extern "C" void kernel_launch(void* const* d_in, const int* in_sizes, int n_in,
                              void* d_out, int out_size, void* d_ws, size_t ws_size,
                              hipStream_t stream) {
    const float* x = (const float*)d_in[0];
    const int* edge = (const int*)d_in[1];
    int E = in_sizes[1] / 2;
    const int* src = edge;
    const int* dst = edge + E;

    const float* w1l = (const float*)d_in[2];
    const float* b1  = (const float*)d_in[3];
    const float* w1r = (const float*)d_in[4];
    const float* g1  = (const float*)d_in[5];
    const float* be1 = (const float*)d_in[6];
    const float* w2l = (const float*)d_in[7];
    const float* b2  = (const float*)d_in[8];
    const float* w2r = (const float*)d_in[9];
    const float* g2  = (const float*)d_in[10];
    const float* be2 = (const float*)d_in[11];
    const float* w3l = (const float*)d_in[12];
    const float* b3  = (const float*)d_in[13];
    const float* w3r = (const float*)d_in[14];
    const float* g3  = (const float*)d_in[15];
    const float* be3 = (const float*)d_in[16];
    const float* w4l = (const float*)d_in[17];
    const float* b4  = (const float*)d_in[18];
    const float* w4r = (const float*)d_in[19];
    const float* g4  = (const float*)d_in[20];
    const float* be4 = (const float*)d_in[21];

    char* ws = (char*)d_ws;
    size_t off = 0;
    auto alloc = [&](size_t bytes) {
        void* p = ws + off;
        off = (off + bytes + 255) & ~(size_t)255;
        return p;
    };
    int* row_ptr = (int*)alloc((N_NODES + 1) * sizeof(int));
    int* blkhist = (int*)alloc((size_t)NBUCK2 * NPART * sizeof(int));
    int* blkoffs = (int*)alloc((size_t)NBUCK2 * NPART * sizeof(int));
    int* bbase2  = (int*)alloc((NBUCK2 + 1) * sizeof(int));
    unsigned int* pairs = (unsigned int*)alloc((size_t)E * sizeof(unsigned int));
    int* colx    = (int*)alloc(((size_t)E + 64) * sizeof(int));
    float* wt1   = (float*)alloc(18 * 64 * sizeof(float));
    unsigned short* bp2 = (unsigned short*)alloc(128 * 128 * sizeof(short));
    unsigned short* bp3 = (unsigned short*)alloc(256 * 128 * sizeof(short));
    unsigned short* bp4 = (unsigned short*)alloc(256 * 128 * sizeof(short));
    float* m9    = (float*)alloc((size_t)N_NODES * 9 * sizeof(float));
    unsigned short* mbf = (unsigned short*)alloc((size_t)N_NODES * 128 * sizeof(short));
    unsigned short* h1  = (unsigned short*)alloc((size_t)N_NODES * 64 * sizeof(short));
    unsigned short* h2  = (unsigned short*)alloc((size_t)N_NODES * 128 * sizeof(short));
    unsigned short* h3  = (unsigned short*)alloc((size_t)N_NODES * 128 * sizeof(short));
    unsigned char* h1f8 = (unsigned char*)alloc((size_t)N_NODES * 64);
    unsigned char* h2f8 = (unsigned char*)alloc((size_t)N_NODES * 128);
    unsigned char* h3f8 = (unsigned char*)alloc((size_t)N_NODES * 128);
    (void)ws_size;

    part_hist<<<NPART, 256, 0, stream>>>(dst, E, blkhist);
    part_offsets<<<1, 64, 0, stream>>>(blkhist, blkoffs, bbase2, row_ptr, E);
    part_scatter<<<NPART, 256, 0, stream>>>(src, dst, E, blkoffs, pairs);
    bucket_build2<<<NBUCK2, 1024, 0, stream>>>(pairs, bbase2, row_ptr, colx);

    wtrans_kernel<<<(18 * 64 + 255) / 256, 256, 0, stream>>>(w1l, w1r, 9, 64, wt1);
    packw_kernel<<<(128 * 128 + 255) / 256, 256, 0, stream>>>(w2l, w2r, 64, bp2);
    packw_kernel<<<(256 * 128 + 255) / 256, 256, 0, stream>>>(w3l, w3r, 128, bp3);
    packw_kernel<<<(256 * 128 + 255) / 256, 256, 0, stream>>>(w4l, w4r, 128, bp4);

    float* out = (float*)d_out;
    int AGB = (N_NODES * 64 + 255) / 256;          // one wave per node (agg9)
    int AGB4 = ((N_NODES + 3) / 4 * 64 + 255) / 256;  // 4 nodes per wave
    int LNB = (N_NODES + 63) / 64;                 // 64 nodes per block

    // layer 1: 9 -> 64 (fp32 compute, bf16 + fp8 out)
    agg9_kernel<<<AGB, 256, 0, stream>>>(x, row_ptr, colx, m9, N_NODES);
    linear_ln_kernel<9, 64, true, __hip_bfloat16><<<LNB, 256, 0, stream>>>(
        m9, x, wt1, b1, g1, be1, (__hip_bfloat16*)h1, h1f8, N_NODES);
    // layer 2: 64 -> 128 (fp8 wide gather, 4 nodes/wave)
    agg64_kernel<<<AGB4, 256, 0, stream>>>(h1f8, row_ptr, colx, mbf, N_NODES);
    mfma_linear_ln<64, true, __hip_bfloat16><<<LNB, 256, 0, stream>>>(
        mbf, h1, bp2, b2, g2, be2, (__hip_bfloat16*)h2, h2f8, N_NODES);
    // layer 3: 128 -> 128 (fp8 wide gather, 4 nodes/wave)
    agg128_kernel<<<AGB4, 256, 0, stream>>>(h2f8, row_ptr, colx, mbf, N_NODES);
    mfma_linear_ln<128, true, __hip_bfloat16><<<LNB, 256, 0, stream>>>(
        mbf, h2, bp3, b3, g3, be3, (__hip_bfloat16*)h3, h3f8, N_NODES);
    // layer 4: 128 -> 128 (fp8 wide gather, 4 nodes/wave, no ReLU, fp32 out)
    agg128_kernel<<<AGB4, 256, 0, stream>>>(h3f8, row_ptr, colx, mbf, N_NODES);
    mfma_linear_ln<128, false, float><<<LNB, 256, 0, stream>>>(
        mbf, h3, bp4, b4, g4, be4, out, (unsigned char*)nullptr, N_NODES);
}

// Round 9
// 389.337 us; speedup vs baseline: 1.2713x; 1.2713x over previous
//
#include <hip/hip_runtime.h>
#include <hip/hip_bf16.h>
#include <math.h>

#define N_NODES 100000
#define EPS 1e-5f
#define B2SH 11
#define NPB2 2048
#define NBUCK2 ((N_NODES + NPB2 - 1) / NPB2)  // 49
#define NPART 256

typedef __attribute__((ext_vector_type(8))) short bf16x8;
typedef __attribute__((ext_vector_type(4))) float f32x4;
typedef __attribute__((ext_vector_type(2))) float f32x2;

__device__ __forceinline__ unsigned short fbits(float f) {
    __hip_bfloat16 h = __float2bfloat16(f);
    return *reinterpret_cast<unsigned short*>(&h);
}
__device__ __forceinline__ void stv(float* p, float y) { *p = y; }
__device__ __forceinline__ void stv(__hip_bfloat16* p, float y) { *p = __float2bfloat16(y); }
__device__ __forceinline__ unsigned char f8enc(float y) {
    return (unsigned char)((unsigned int)__builtin_amdgcn_cvt_pk_fp8_f32(y, y, 0, false) & 0xffu);
}

// ---------------- atomic-free two-level CSR build ----------------
__global__ void part_hist(const int* __restrict__ dst, int E, int* __restrict__ blkhist) {
    __shared__ int h[NBUCK2];
    int b = blockIdx.x;
    int slice = (E + NPART - 1) / NPART;
    int s0 = b * slice;
    int s1 = min(E, s0 + slice);
    for (int i = threadIdx.x; i < NBUCK2; i += 256) h[i] = 0;
    __syncthreads();
    for (int e = s0 + threadIdx.x; e < s1; e += 256) atomicAdd(&h[dst[e] >> B2SH], 1);
    __syncthreads();
    for (int i = threadIdx.x; i < NBUCK2; i += 256) blkhist[i * NPART + b] = h[i];
}

__global__ void part_offsets(const int* __restrict__ blkhist, int* __restrict__ blkoffs,
                             int* __restrict__ bbase2, int* __restrict__ row_ptr, int E) {
    __shared__ int tot[NBUCK2];
    __shared__ int sbase[NBUCK2 + 1];
    int j = threadIdx.x;
    if (j < NBUCK2) {
        int run = 0;
#pragma unroll 8
        for (int b = 0; b < NPART; ++b) {
            blkoffs[j * NPART + b] = run;
            run += blkhist[j * NPART + b];
        }
        tot[j] = run;
    }
    __syncthreads();
    if (j == 0) {
        int run = 0;
        for (int i = 0; i < NBUCK2; ++i) {
            sbase[i] = run;
            run += tot[i];
        }
        sbase[NBUCK2] = run;
        row_ptr[N_NODES] = E;
    }
    __syncthreads();
    if (j <= NBUCK2) bbase2[j] = sbase[j];
    if (j < NBUCK2) {
        int base = sbase[j];
#pragma unroll 8
        for (int b = 0; b < NPART; ++b) blkoffs[j * NPART + b] += base;
    }
}

__global__ void part_scatter(const int* __restrict__ src, const int* __restrict__ dst, int E,
                             const int* __restrict__ blkoffs, unsigned int* __restrict__ pairs) {
    __shared__ int pos[NBUCK2];
    int b = blockIdx.x;
    int slice = (E + NPART - 1) / NPART;
    int s0 = b * slice;
    int s1 = min(E, s0 + slice);
    for (int i = threadIdx.x; i < NBUCK2; i += 256) pos[i] = blkoffs[i * NPART + b];
    __syncthreads();
    for (int e = s0 + threadIdx.x; e < s1; e += 256) {
        int d = dst[e];
        int jb = d >> B2SH;
        int p = atomicAdd(&pos[jb], 1);
        pairs[p] = ((unsigned int)src[e] << B2SH) | (unsigned int)(d & (NPB2 - 1));
    }
}

__global__ __launch_bounds__(1024) void bucket_build2(const unsigned int* __restrict__ pairs,
                                                      const int* __restrict__ bbase2,
                                                      int* __restrict__ row_ptr,
                                                      int* __restrict__ col) {
    __shared__ int lcnt[NPB2];
    __shared__ int lofs[NPB2];
    __shared__ int part[1024];
    int bk = blockIdx.x;
    int base = bbase2[bk];
    int cntb = bbase2[bk + 1] - base;
    int node0 = bk << B2SH;
    int t = threadIdx.x;
    lcnt[t] = 0;
    lcnt[t + 1024] = 0;
    __syncthreads();
    for (int i = t; i < cntb; i += 1024) atomicAdd(&lcnt[pairs[base + i] & (NPB2 - 1)], 1);
    __syncthreads();
    int a0 = lcnt[2 * t], a1 = lcnt[2 * t + 1];
    part[t] = a0 + a1;
    __syncthreads();
    for (int off = 1; off < 1024; off <<= 1) {
        int v = (t >= off) ? part[t - off] : 0;
        __syncthreads();
        part[t] += v;
        __syncthreads();
    }
    int excl = part[t] - (a0 + a1);
    lofs[2 * t] = excl;
    lofs[2 * t + 1] = excl + a0;
    __syncthreads();
#pragma unroll
    for (int k = 0; k < 2; ++k) {
        int ln = 2 * t + k;
        int node = node0 + ln;
        if (node < N_NODES) row_ptr[node] = base + lofs[ln];
    }
    lcnt[t] = 0;
    lcnt[t + 1024] = 0;
    __syncthreads();
    for (int i = t; i < cntb; i += 1024) {
        unsigned int v = pairs[base + i];
        int ld = v & (NPB2 - 1);
        int s = v >> B2SH;
        int p = base + lofs[ld] + atomicAdd(&lcnt[ld], 1);
        col[p] = s;
    }
}

// ---------------- aggregation ----------------
// layer1: x fp32, d=9; 7 lane-groups of 9; predicated unroll of stride-7 walk
__global__ void agg9_kernel(const float* __restrict__ x, const int* __restrict__ row_ptr,
                            const int* __restrict__ col, float* __restrict__ mean, int n) {
    int node = (blockIdx.x * blockDim.x + threadIdx.x) >> 6;
    int lane = threadIdx.x & 63;
    int wv = threadIdx.x >> 6;
    __shared__ float red[4][64];
    float acc = 0.f;
    int start = 0, end = 0;
    if (node < n) {
        start = row_ptr[node];
        end = row_ptr[node + 1];
        int g = lane / 9;
        int f = lane - g * 9;
        if (g < 7 && end > start) {
            for (int p = start + g; p < end; p += 28) {
#pragma unroll
                for (int i = 0; i < 4; ++i) {
                    int q = p + i * 7;
                    int idx = (q < end) ? q : end - 1;
                    float v = x[(size_t)col[idx] * 9 + f];
                    if (q >= end) v = 0.f;
                    acc += v;
                }
            }
        }
    }
    red[wv][lane] = acc;
    __syncthreads();
    if (node < n && lane < 9) {
        float s = red[wv][lane];
#pragma unroll
        for (int k = 1; k < 7; ++k) s += red[wv][lane + 9 * k];
        float inv = 1.f / fmaxf((float)(end - start), 1.f);
        mean[(size_t)node * 9 + lane] = s * inv;
    }
}

// packed fp8 -> f32 accumulate of one 16B chunk into 16 accumulators
__device__ __forceinline__ void acc16_fp8(const uint4& v, float* acc) {
#pragma unroll
    for (int d = 0; d < 4; ++d) {
        unsigned int u = (&v.x)[d];
        f32x2 a = __builtin_amdgcn_cvt_pk_f32_fp8(u, false);
        f32x2 b = __builtin_amdgcn_cvt_pk_f32_fp8(u, true);
        acc[d * 4 + 0] += a[0];
        acc[d * 4 + 1] += a[1];
        acc[d * 4 + 2] += b[0];
        acc[d * 4 + 3] += b[1];
    }
}

// fp8 d=64: one wave per node; lane = (e<<2)|c, e in [0,16) edge-slot, c in [0,4) 16B chunk.
// 2 independent uint4 gathers per iteration (covers 32 edges).
__global__ __launch_bounds__(256) void agg64_kernel(const unsigned char* __restrict__ h8,
                                                    const int* __restrict__ row_ptr,
                                                    const int* __restrict__ col,
                                                    unsigned short* __restrict__ mean, int n) {
    int node = (blockIdx.x * blockDim.x + threadIdx.x) >> 6;
    int lane = threadIdx.x & 63;
    if (node >= n) return;
    int e = lane >> 2, c = lane & 3;
    int start = row_ptr[node], end = row_ptr[node + 1];
    int deg = end - start;
    if (deg <= 0) {
        mean[(size_t)node * 64 + lane] = 0;
        return;
    }
    float acc[16];
#pragma unroll
    for (int j = 0; j < 16; ++j) acc[j] = 0.f;
    const unsigned char* hc = h8 + c * 16;
    for (int p = start; p < end; p += 32) {
        int qa = p + e;
        int qb = p + 16 + e;
        int ia = col[(qa < end) ? qa : end - 1];
        int ib = col[(qb < end) ? qb : end - 1];
        uint4 va = *(const uint4*)(hc + ((size_t)ia << 6));
        uint4 vb = *(const uint4*)(hc + ((size_t)ib << 6));
        if (qa >= end) va = (uint4){0u, 0u, 0u, 0u};
        if (qb >= end) vb = (uint4){0u, 0u, 0u, 0u};
        acc16_fp8(va, acc);
        acc16_fp8(vb, acc);
    }
#pragma unroll
    for (int j = 0; j < 16; ++j) {
        acc[j] += __shfl_xor(acc[j], 4);
        acc[j] += __shfl_xor(acc[j], 8);
        acc[j] += __shfl_xor(acc[j], 16);
        acc[j] += __shfl_xor(acc[j], 32);
    }
    if (e == 0) {
        float inv = 1.f / (float)deg;
        unsigned int w[8];
#pragma unroll
        for (int j = 0; j < 8; ++j) {
            unsigned int lo = fbits(acc[2 * j] * inv);
            unsigned int hi = fbits(acc[2 * j + 1] * inv);
            w[j] = lo | (hi << 16);
        }
        unsigned short* mrow = mean + (size_t)node * 64 + c * 16;
        *(uint4*)(mrow) = (uint4){w[0], w[1], w[2], w[3]};
        *(uint4*)(mrow + 8) = (uint4){w[4], w[5], w[6], w[7]};
    }
}

// fp8 d=128: one wave per node; lane = (e<<3)|c, e in [0,8) edge-slot, c in [0,8) chunk.
// 4 independent uint4 gathers per iteration (covers 32 edges).
__global__ __launch_bounds__(256) void agg128_kernel(const unsigned char* __restrict__ h8,
                                                     const int* __restrict__ row_ptr,
                                                     const int* __restrict__ col,
                                                     unsigned short* __restrict__ mean, int n) {
    int node = (blockIdx.x * blockDim.x + threadIdx.x) >> 6;
    int lane = threadIdx.x & 63;
    if (node >= n) return;
    int e = lane >> 3, c = lane & 7;
    int start = row_ptr[node], end = row_ptr[node + 1];
    int deg = end - start;
    if (deg <= 0) {
        *(unsigned int*)&mean[(size_t)node * 128 + lane * 2] = 0u;
        return;
    }
    float acc[16];
#pragma unroll
    for (int j = 0; j < 16; ++j) acc[j] = 0.f;
    const unsigned char* hc = h8 + c * 16;
    for (int p = start; p < end; p += 32) {
        uint4 v[4];
        bool m[4];
#pragma unroll
        for (int j = 0; j < 4; ++j) {
            int q = p + 8 * j + e;
            m[j] = q < end;
            int idx = col[m[j] ? q : end - 1];
            v[j] = *(const uint4*)(hc + ((size_t)idx << 7));
        }
#pragma unroll
        for (int j = 0; j < 4; ++j) {
            if (!m[j]) v[j] = (uint4){0u, 0u, 0u, 0u};
            acc16_fp8(v[j], acc);
        }
    }
#pragma unroll
    for (int j = 0; j < 16; ++j) {
        acc[j] += __shfl_xor(acc[j], 8);
        acc[j] += __shfl_xor(acc[j], 16);
        acc[j] += __shfl_xor(acc[j], 32);
    }
    if (e == 0) {
        float inv = 1.f / (float)deg;
        unsigned int w[8];
#pragma unroll
        for (int j = 0; j < 8; ++j) {
            unsigned int lo = fbits(acc[2 * j] * inv);
            unsigned int hi = fbits(acc[2 * j + 1] * inv);
            w[j] = lo | (hi << 16);
        }
        unsigned short* mrow = mean + (size_t)node * 128 + c * 16;
        *(uint4*)(mrow) = (uint4){w[0], w[1], w[2], w[3]};
        *(uint4*)(mrow + 8) = (uint4){w[4], w[5], w[6], w[7]};
    }
}

// ---------------- weight prep ----------------
__global__ void wtrans_kernel(const float* __restrict__ wl, const float* __restrict__ wr,
                              int din, int dout, float* __restrict__ wt) {
    int i = blockIdx.x * blockDim.x + threadIdx.x;
    int K2 = 2 * din;
    if (i >= K2 * dout) return;
    int k = i / dout, j = i % dout;
    wt[k * dout + j] = (k < din) ? wl[j * din + k] : wr[j * din + (k - din)];
}

__global__ void packw_kernel(const float* __restrict__ wl, const float* __restrict__ wr,
                             int din, unsigned short* __restrict__ bpack) {
    int K2 = 2 * din;
    int total = K2 * 128;
    int i = blockIdx.x * 256 + threadIdx.x;
    if (i >= total) return;
    int e = i & 7;
    int lane = (i >> 3) & 63;
    int rest = i >> 9;
    int KSTEPS = din / 16;
    int t = rest / KSTEPS, ks = rest % KSTEPS;
    int j = t * 16 + (lane & 15);
    int k = ks * 32 + (lane >> 4) * 8 + e;
    float w = (k < din) ? wl[j * din + k] : wr[j * din + (k - din)];
    bpack[i] = fbits(w);
}

// ---------------- layer1 fp32 linear + LN + ReLU (+ fp8 shadow) ----------------
template <int DIN, int DOUT, bool RELU, typename OT>
__global__ __launch_bounds__(256) void linear_ln_kernel(
    const float* __restrict__ meanp, const float* __restrict__ hp,
    const float* __restrict__ wt, const float* __restrict__ bias,
    const float* __restrict__ g, const float* __restrict__ be,
    OT* __restrict__ out, unsigned char* __restrict__ out8, int n) {
    constexpr int K2 = 2 * DIN;
    constexpr int NCOL = DOUT / 4;
    constexpr int NROW = 256 / NCOL;
    constexpr int TN = 4 * NROW;
    constexpr int ASTR = TN + 4;
    constexpr int OSTR = DOUT + 4;
    constexpr int SMEMF = (K2 * ASTR > TN * OSTR) ? K2 * ASTR : TN * OSTR;
    __shared__ float smem[SMEMF];

    int tid = threadIdx.x;
    int n0base = blockIdx.x * TN;

    for (int idx = tid; idx < TN * K2; idx += 256) {
        int nn = idx / K2;
        int k = idx % K2;
        int node = n0base + nn;
        float v = 0.f;
        if (node < n)
            v = (k < DIN) ? meanp[(size_t)node * DIN + k] : hp[(size_t)node * DIN + (k - DIN)];
        smem[k * ASTR + nn] = v;
    }
    __syncthreads();

    int colt = tid % NCOL;
    int rowt = tid / NCOL;
    int j0 = colt * 4;
    int nn0 = rowt * 4;

    float acc[4][4];
#pragma unroll
    for (int i = 0; i < 4; ++i)
#pragma unroll
        for (int j = 0; j < 4; ++j) acc[i][j] = 0.f;

#pragma unroll 2
    for (int k = 0; k < K2; ++k) {
        float4 a = *(const float4*)&smem[k * ASTR + nn0];
        float4 w = *(const float4*)&wt[k * DOUT + j0];
        acc[0][0] = fmaf(a.x, w.x, acc[0][0]);
        acc[0][1] = fmaf(a.x, w.y, acc[0][1]);
        acc[0][2] = fmaf(a.x, w.z, acc[0][2]);
        acc[0][3] = fmaf(a.x, w.w, acc[0][3]);
        acc[1][0] = fmaf(a.y, w.x, acc[1][0]);
        acc[1][1] = fmaf(a.y, w.y, acc[1][1]);
        acc[1][2] = fmaf(a.y, w.z, acc[1][2]);
        acc[1][3] = fmaf(a.y, w.w, acc[1][3]);
        acc[2][0] = fmaf(a.z, w.x, acc[2][0]);
        acc[2][1] = fmaf(a.z, w.y, acc[2][1]);
        acc[2][2] = fmaf(a.z, w.z, acc[2][2]);
        acc[2][3] = fmaf(a.z, w.w, acc[2][3]);
        acc[3][0] = fmaf(a.w, w.x, acc[3][0]);
        acc[3][1] = fmaf(a.w, w.y, acc[3][1]);
        acc[3][2] = fmaf(a.w, w.z, acc[3][2]);
        acc[3][3] = fmaf(a.w, w.w, acc[3][3]);
    }
    __syncthreads();

    float4 bj = *(const float4*)&bias[j0];
#pragma unroll
    for (int i = 0; i < 4; ++i) {
        float4 o;
        o.x = acc[i][0] + bj.x;
        o.y = acc[i][1] + bj.y;
        o.z = acc[i][2] + bj.z;
        o.w = acc[i][3] + bj.w;
        *(float4*)&smem[(nn0 + i) * OSTR + j0] = o;
    }
    __syncthreads();

    int wid = tid >> 6, lane = tid & 63;
    for (int nn = wid; nn < TN; nn += 4) {
        int node = n0base + nn;
        if (node >= n) continue;
        float v0 = smem[nn * OSTR + lane];
        float v1 = (DOUT == 128) ? smem[nn * OSTR + 64 + lane] : 0.f;
        float s = v0 + v1;
        float ss = v0 * v0 + v1 * v1;
#pragma unroll
        for (int off = 32; off > 0; off >>= 1) {
            s += __shfl_xor(s, off);
            ss += __shfl_xor(ss, off);
        }
        float mu = s / DOUT;
        float var = ss / DOUT - mu * mu;
        float inv = rsqrtf(var + EPS);
        float y0 = (v0 - mu) * inv * g[lane] + be[lane];
        if (RELU) y0 = fmaxf(y0, 0.f);
        stv(&out[(size_t)node * DOUT + lane], y0);
        if (out8) out8[(size_t)node * DOUT + lane] = f8enc(y0);
        if (DOUT == 128) {
            float y1 = (v1 - mu) * inv * g[64 + lane] + be[64 + lane];
            if (RELU) y1 = fmaxf(y1, 0.f);
            stv(&out[(size_t)node * DOUT + 64 + lane], y1);
            if (out8) out8[(size_t)node * DOUT + 64 + lane] = f8enc(y1);
        }
    }
}

// ---------------- bf16 MFMA linear (concat-K) + LN + optional ReLU + fp8 shadow
template <int DIN, bool RELU, typename OT>
__global__ __launch_bounds__(256) void mfma_linear_ln(
    const unsigned short* __restrict__ meanb, const unsigned short* __restrict__ hb,
    const unsigned short* __restrict__ bpack, const float* __restrict__ bias,
    const float* __restrict__ g, const float* __restrict__ be, OT* __restrict__ out,
    unsigned char* __restrict__ out8, int n) {
    constexpr int KSTEPS = DIN / 16;
    int tid = threadIdx.x;
    int w = tid >> 6, l = tid & 63;
    int n0 = blockIdx.x * 64 + w * 16;
    int arow = l & 15;
    int koff = (l >> 4) * 8;
    int anode = n0 + arow;
    if (anode >= n) anode = n - 1;
    const unsigned short* mrow = meanb + (size_t)anode * DIN;
    const unsigned short* hrow = hb + (size_t)anode * DIN;

    f32x4 acc[8];
#pragma unroll
    for (int t = 0; t < 8; ++t) acc[t] = (f32x4){0.f, 0.f, 0.f, 0.f};

#pragma unroll
    for (int ks = 0; ks < KSTEPS; ++ks) {
        int k = ks * 32 + koff;
        const unsigned short* ap = (k < DIN) ? (mrow + k) : (hrow + (k - DIN));
        bf16x8 a = *(const bf16x8*)ap;
#pragma unroll
        for (int t = 0; t < 8; ++t) {
            bf16x8 b = *(const bf16x8*)(bpack + (((size_t)t * KSTEPS + ks) * 64 + l) * 8);
            acc[t] = __builtin_amdgcn_mfma_f32_16x16x32_bf16(a, b, acc[t], 0, 0, 0);
        }
    }

    int jbase = l & 15;
    float bj[8], gj[8], bej[8];
#pragma unroll
    for (int t = 0; t < 8; ++t) {
        bj[t] = bias[t * 16 + jbase];
        gj[t] = g[t * 16 + jbase];
        bej[t] = be[t * 16 + jbase];
    }
#pragma unroll
    for (int r = 0; r < 4; ++r) {
        float v[8];
        float s = 0.f, ss = 0.f;
#pragma unroll
        for (int t = 0; t < 8; ++t) {
            v[t] = acc[t][r] + bj[t];
            s += v[t];
            ss += v[t] * v[t];
        }
#pragma unroll
        for (int off = 1; off < 16; off <<= 1) {
            s += __shfl_xor(s, off);
            ss += __shfl_xor(ss, off);
        }
        float mu = s * (1.f / 128.f);
        float var = ss * (1.f / 128.f) - mu * mu;
        float inv = rsqrtf(var + EPS);
        int node = n0 + (l >> 4) * 4 + r;
        if (node < n) {
#pragma unroll
            for (int t = 0; t < 8; ++t) {
                float y = (v[t] - mu) * inv * gj[t] + bej[t];
                if (RELU) y = fmaxf(y, 0.f);
                stv(&out[(size_t)node * 128 + t * 16 + jbase], y);
                if (out8) out8[(size_t)node * 128 + t * 16 + jbase] = f8enc(y);
            }
        }
    }
}

extern "C" void kernel_launch(void* const* d_in, const int* in_sizes, int n_in,
                              void* d_out, int out_size, void* d_ws, size_t ws_size,
                              hipStream_t stream) {
    const float* x = (const float*)d_in[0];
    const int* edge = (const int*)d_in[1];
    int E = in_sizes[1] / 2;
    const int* src = edge;
    const int* dst = edge + E;

    const float* w1l = (const float*)d_in[2];
    const float* b1  = (const float*)d_in[3];
    const float* w1r = (const float*)d_in[4];
    const float* g1  = (const float*)d_in[5];
    const float* be1 = (const float*)d_in[6];
    const float* w2l = (const float*)d_in[7];
    const float* b2  = (const float*)d_in[8];
    const float* w2r = (const float*)d_in[9];
    const float* g2  = (const float*)d_in[10];
    const float* be2 = (const float*)d_in[11];
    const float* w3l = (const float*)d_in[12];
    const float* b3  = (const float*)d_in[13];
    const float* w3r = (const float*)d_in[14];
    const float* g3  = (const float*)d_in[15];
    const float* be3 = (const float*)d_in[16];
    const float* w4l = (const float*)d_in[17];
    const float* b4  = (const float*)d_in[18];
    const float* w4r = (const float*)d_in[19];
    const float* g4  = (const float*)d_in[20];
    const float* be4 = (const float*)d_in[21];

    char* ws = (char*)d_ws;
    size_t off = 0;
    auto alloc = [&](size_t bytes) {
        void* p = ws + off;
        off = (off + bytes + 255) & ~(size_t)255;
        return p;
    };
    int* row_ptr = (int*)alloc((N_NODES + 1) * sizeof(int));
    int* blkhist = (int*)alloc((size_t)NBUCK2 * NPART * sizeof(int));
    int* blkoffs = (int*)alloc((size_t)NBUCK2 * NPART * sizeof(int));
    int* bbase2  = (int*)alloc((NBUCK2 + 1) * sizeof(int));
    unsigned int* pairs = (unsigned int*)alloc((size_t)E * sizeof(unsigned int));
    int* colx    = (int*)alloc(((size_t)E + 64) * sizeof(int));
    float* wt1   = (float*)alloc(18 * 64 * sizeof(float));
    unsigned short* bp2 = (unsigned short*)alloc(128 * 128 * sizeof(short));
    unsigned short* bp3 = (unsigned short*)alloc(256 * 128 * sizeof(short));
    unsigned short* bp4 = (unsigned short*)alloc(256 * 128 * sizeof(short));
    float* m9    = (float*)alloc((size_t)N_NODES * 9 * sizeof(float));
    unsigned short* mbf = (unsigned short*)alloc((size_t)N_NODES * 128 * sizeof(short));
    unsigned short* h1  = (unsigned short*)alloc((size_t)N_NODES * 64 * sizeof(short));
    unsigned short* h2  = (unsigned short*)alloc((size_t)N_NODES * 128 * sizeof(short));
    unsigned short* h3  = (unsigned short*)alloc((size_t)N_NODES * 128 * sizeof(short));
    unsigned char* h1f8 = (unsigned char*)alloc((size_t)N_NODES * 64);
    unsigned char* h2f8 = (unsigned char*)alloc((size_t)N_NODES * 128);
    unsigned char* h3f8 = (unsigned char*)alloc((size_t)N_NODES * 128);
    (void)ws_size;

    part_hist<<<NPART, 256, 0, stream>>>(dst, E, blkhist);
    part_offsets<<<1, 64, 0, stream>>>(blkhist, blkoffs, bbase2, row_ptr, E);
    part_scatter<<<NPART, 256, 0, stream>>>(src, dst, E, blkoffs, pairs);
    bucket_build2<<<NBUCK2, 1024, 0, stream>>>(pairs, bbase2, row_ptr, colx);

    wtrans_kernel<<<(18 * 64 + 255) / 256, 256, 0, stream>>>(w1l, w1r, 9, 64, wt1);
    packw_kernel<<<(128 * 128 + 255) / 256, 256, 0, stream>>>(w2l, w2r, 64, bp2);
    packw_kernel<<<(256 * 128 + 255) / 256, 256, 0, stream>>>(w3l, w3r, 128, bp3);
    packw_kernel<<<(256 * 128 + 255) / 256, 256, 0, stream>>>(w4l, w4r, 128, bp4);

    float* out = (float*)d_out;
    int AGB = (N_NODES * 64 + 255) / 256;  // one wave per node
    int LNB = (N_NODES + 63) / 64;         // 64 nodes per block

    // layer 1: 9 -> 64 (fp32 compute, bf16 + fp8 out)
    agg9_kernel<<<AGB, 256, 0, stream>>>(x, row_ptr, colx, m9, N_NODES);
    linear_ln_kernel<9, 64, true, __hip_bfloat16><<<LNB, 256, 0, stream>>>(
        m9, x, wt1, b1, g1, be1, (__hip_bfloat16*)h1, h1f8, N_NODES);
    // layer 2: 64 -> 128 (fp8 wide gather)
    agg64_kernel<<<AGB, 256, 0, stream>>>(h1f8, row_ptr, colx, mbf, N_NODES);
    mfma_linear_ln<64, true, __hip_bfloat16><<<LNB, 256, 0, stream>>>(
        mbf, h1, bp2, b2, g2, be2, (__hip_bfloat16*)h2, h2f8, N_NODES);
    // layer 3: 128 -> 128 (fp8 wide gather)
    agg128_kernel<<<AGB, 256, 0, stream>>>(h2f8, row_ptr, colx, mbf, N_NODES);
    mfma_linear_ln<128, true, __hip_bfloat16><<<LNB, 256, 0, stream>>>(
        mbf, h2, bp3, b3, g3, be3, (__hip_bfloat16*)h3, h3f8, N_NODES);
    // layer 4: 128 -> 128 (fp8 wide gather, no ReLU, fp32 out)
    agg128_kernel<<<AGB, 256, 0, stream>>>(h3f8, row_ptr, colx, mbf, N_NODES);
    mfma_linear_ln<128, false, float><<<LNB, 256, 0, stream>>>(
        mbf, h3, bp4, b4, g4, be4, out, (unsigned char*)nullptr, N_NODES);
}